// Round 9
// baseline (98.651 us; speedup 1.0000x reference)
//
#include <hip/hip_runtime.h>
#include <hip/hip_bf16.h>

#define MARGIN  0.2f
#define NEG_INF -1e30f
#define POS_INF 1e30f

#define B_SZ 8192
#define D_SZ 128
#define CS   16                      // col splits (512 cols each)
#define BLK_COLS 512
#define PHASE_COLS 64
#define NPH (BLK_COLS / PHASE_COLS)  // 8
#define NBUF 3                       // LDS ring, prefetch distance 2

typedef __bf16 bf16x8 __attribute__((ext_vector_type(8)));
typedef float  f32x4  __attribute__((ext_vector_type(4)));
typedef float  f32x16 __attribute__((ext_vector_type(16)));

// ---------------- Kernel 1: fp32 -> bf16 convert (8 elems/thread) ----------------
__global__ __launch_bounds__(256) void k_convert(const float* __restrict__ in,
                                                 __bf16* __restrict__ out) {
    int i = (blockIdx.x * 256 + threadIdx.x) * 8;
    float4 v0 = *reinterpret_cast<const float4*>(in + i);
    float4 v1 = *reinterpret_cast<const float4*>(in + i + 4);
    bf16x8 o;
    o[0] = (__bf16)v0.x; o[1] = (__bf16)v0.y; o[2] = (__bf16)v0.z; o[3] = (__bf16)v0.w;
    o[4] = (__bf16)v1.x; o[5] = (__bf16)v1.y; o[6] = (__bf16)v1.z; o[7] = (__bf16)v1.w;
    *reinterpret_cast<bf16x8*>(out + i) = o;
}

// ---------------- Kernel 2: fused GEMM + hard mining (32x32x16, T4 pipeline) ----
// 1024 blocks = 64 rb (128 rows) x 16 cs (512 cols), XCD-contiguous swizzle.
// 4 waves; wave w owns rows [rb*128+w*32,+32). B staged to LDS ring (3 bufs,
// 16KB each) via global_load_lds in chunked fragment order (chunk(tile,kf)=1KB,
// lane-linear on both DMA-write and ds_read_b128 -> conflict-free).
// Counted-vmcnt pipeline: phase p issues stage(p+2), computes buf(p%3), then
// waits vmcnt(4) (p+1's loads landed, p+2's stay in flight across the barrier).
__global__ __launch_bounds__(256, 3) void k_mine(const __bf16* __restrict__ imb,
                                                 const int* __restrict__ ids,
                                                 float* __restrict__ wsmax,
                                                 float* __restrict__ wsmin) {
    __shared__ __bf16 bpanel[NBUF][PHASE_COLS * D_SZ];   // 3 x 16KB

    const int bid = blockIdx.x;
    const int wg  = (bid & 7) * 128 + (bid >> 3);   // bijective (1024%8==0)
    const int rb  = wg & 63;
    const int cs  = wg >> 6;

    const int tid  = threadIdx.x;
    const int w    = tid >> 6;
    const int lane = tid & 63;
    const int half = lane >> 5;      // 0/1 -> K sub-chunk
    const int l5   = lane & 31;      // row (A) / col (B)

    const int rowbase = rb * 128 + w * 32;
    const int col0    = cs * BLK_COLS;

    // staging role: wave w stages chunks [w*4, w*4+4) ; tile = w>>1, kf0 = (w&1)*4
    const int s_tile = w >> 1;
    const int s_kf0  = (w & 1) * 4;

    // A fragments: 8 kf chunks (row = l5, k = kf*16 + half*8 + j)
    bf16x8 afrag[8];
    {
        const __bf16* p = imb + (size_t)(rowbase + l5) * D_SZ + half * 8;
        #pragma unroll
        for (int kf = 0; kf < 8; ++kf)
            afrag[kf] = *reinterpret_cast<const bf16x8*>(p + kf * 16);
    }
    // row ids for C layout: row = (r&3) + 8*(r>>2) + 4*half
    int rid[16];
    #pragma unroll
    for (int r = 0; r < 16; ++r)
        rid[r] = ids[rowbase + (r & 3) + 8 * (r >> 2) + 4 * half];

    // prologue: stage phases 0 and 1 (issued after reg loads -> clean vmcnt FIFO)
    #pragma unroll
    for (int pp = 0; pp < 2; ++pp) {
        const __bf16* src = imb + (size_t)(col0 + pp * PHASE_COLS + s_tile * 32 + l5) * D_SZ
                            + s_kf0 * 16 + half * 8;
        #pragma unroll
        for (int j = 0; j < 4; ++j)
            __builtin_amdgcn_global_load_lds(
                (const __attribute__((address_space(1))) unsigned int*)(src + j * 16),
                (__attribute__((address_space(3))) unsigned int*)(&bpanel[pp][(s_tile * 8 + s_kf0 + j) * 512]),
                16, 0, 0);
    }
    asm volatile("s_waitcnt vmcnt(4)" ::: "memory");   // phase-0 loads landed
    __builtin_amdgcn_s_barrier();

    float mxn[16], mnp[16];
    #pragma unroll
    for (int r = 0; r < 16; ++r) { mxn[r] = NEG_INF; mnp[r] = POS_INF; }

    #pragma unroll 1
    for (int p = 0; p < NPH; ++p) {
        if (p + 2 < NPH) {   // stage(p+2) into ring slot; stays in flight past barrier
            const int bs = (p + 2) % NBUF;
            const __bf16* src = imb + (size_t)(col0 + (p + 2) * PHASE_COLS + s_tile * 32 + l5) * D_SZ
                                + s_kf0 * 16 + half * 8;
            #pragma unroll
            for (int j = 0; j < 4; ++j)
                __builtin_amdgcn_global_load_lds(
                    (const __attribute__((address_space(1))) unsigned int*)(src + j * 16),
                    (__attribute__((address_space(3))) unsigned int*)(&bpanel[bs][(s_tile * 8 + s_kf0 + j) * 512]),
                    16, 0, 0);
        }
        const int buf = p % NBUF;
        #pragma unroll
        for (int t = 0; t < 2; ++t) {   // both tiles exposed -> 2 independent MFMA chains
            const __bf16* bbase = &bpanel[buf][t * 4096] + (size_t)lane * 8;
            f32x16 acc = {};
            #pragma unroll
            for (int kf = 0; kf < 8; ++kf) {
                bf16x8 bfr = *reinterpret_cast<const bf16x8*>(bbase + kf * 512);
                acc = __builtin_amdgcn_mfma_f32_32x32x16_bf16(afrag[kf], bfr, acc, 0, 0, 0);
            }
            const int cid = ids[col0 + p * PHASE_COLS + t * 32 + l5];  // L1-hit, consumed below
            // diag dropped: raw diag = ||v||^2 >= 0, absorbed by min(0,.) in k_final
            #pragma unroll
            for (int r = 0; r < 16; ++r) {
                float sv   = acc[r];
                bool  same = (rid[r] == cid);
                mxn[r] = fmaxf(mxn[r], same ? NEG_INF : sv);
                mnp[r] = fminf(mnp[r], same ? sv : POS_INF);
            }
        }
        if (p + 2 < NPH) {
            asm volatile("s_waitcnt vmcnt(4)" ::: "memory");  // p+1 landed; p+2 in flight
        } else {
            asm volatile("s_waitcnt vmcnt(0)" ::: "memory");  // tail: drain
        }
        __builtin_amdgcn_s_barrier();
    }

    // epilogue: butterfly over 32 lanes sharing each row set; writers at l5==0
    #pragma unroll
    for (int r = 0; r < 16; ++r) {
        float mx = mxn[r];
        float mn = mnp[r];
        #pragma unroll
        for (int m = 1; m < 32; m <<= 1) {
            mx = fmaxf(mx, __shfl_xor(mx, m, 64));
            mn = fminf(mn, __shfl_xor(mn, m, 64));
        }
        if (l5 == 0) {
            int row = rowbase + (r & 3) + 8 * (r >> 2) + 4 * half;
            wsmax[(size_t)row * CS + cs] = mx;
            wsmin[(size_t)row * CS + cs] = mn;
        }
    }
}

// ---------------- Kernel 3: final reduce ----------------
__global__ __launch_bounds__(256) void k_final(const float* __restrict__ wsmax,
                                               const float* __restrict__ wsmin,
                                               float* __restrict__ out) {
    int r = blockIdx.x * 256 + threadIdx.x;
    float mx = NEG_INF;
    float mn = 0.0f;   // zeroed diagonal is always a positive candidate
    #pragma unroll
    for (int c = 0; c < CS; c += 4) {
        f32x4 vx = *reinterpret_cast<const f32x4*>(wsmax + (size_t)r * CS + c);
        f32x4 vn = *reinterpret_cast<const f32x4*>(wsmin + (size_t)r * CS + c);
        mx = fmaxf(mx, fmaxf(fmaxf(vx[0], vx[1]), fmaxf(vx[2], vx[3])));
        mn = fminf(mn, fminf(fminf(vn[0], vn[1]), fminf(vn[2], vn[3])));
    }
    float cost = fmaxf(MARGIN + mx - mn, 0.0f);
    #pragma unroll
    for (int m = 1; m < 64; m <<= 1)
        cost += __shfl_xor(cost, m, 64);
    __shared__ float part[4];
    if ((threadIdx.x & 63) == 0) part[threadIdx.x >> 6] = cost;
    __syncthreads();
    if (threadIdx.x == 0)
        atomicAdd(out, part[0] + part[1] + part[2] + part[3]);
}

extern "C" void kernel_launch(void* const* d_in, const int* in_sizes, int n_in,
                              void* d_out, int out_size, void* d_ws, size_t ws_size,
                              hipStream_t stream) {
    const float* im  = (const float*)d_in[0];
    const int*   ids = (const int*)d_in[1];
    float*       out = (float*)d_out;

    __bf16* imb   = (__bf16*)d_ws;                                    // 2 MB
    float*  wsmax = (float*)((char*)d_ws + (size_t)B_SZ * D_SZ * 2);  // 512 KB
    float*  wsmin = wsmax + (size_t)B_SZ * CS;                        // 512 KB

    hipMemsetAsync(d_out, 0, sizeof(float), stream);

    k_convert<<<(B_SZ * D_SZ) / (256 * 8), 256, 0, stream>>>(im, imb);
    k_mine<<<64 * CS, 256, 0, stream>>>(imb, ids, wsmax, wsmin);
    k_final<<<B_SZ / 256, 256, 0, stream>>>(wsmax, wsmin, out);
}